// Round 1
// baseline (8989.652 us; speedup 1.0000x reference)
//
#include <hip/hip_runtime.h>
#include <hip/hip_bf16.h>
#include <math.h>

namespace {

constexpr int Tt   = 1024;
constexpr int BT   = 2048;     // B*T
constexpr int Bb   = 2;
constexpr int C    = 768;
constexpr int Vv   = 50257;
constexpr int Ll   = 2;
constexpr int Ee   = 8;
constexpr int ER   = 6;
constexpr int ET   = 2;
constexpr int Hh   = 3072;
constexpr int H2   = 1536;
constexpr int CAP  = 2048;     // max rows per expert
constexpr size_t NB = (size_t)BT * C;

__device__ __forceinline__ float sigf(float x){ return 1.f/(1.f+expf(-x)); }

// ---------------- small kernels ----------------

__global__ void __launch_bounds__(256) embed_kernel(const int* __restrict__ idx,
    const float* __restrict__ embW, float* __restrict__ x){
  int row = blockIdx.x;
  int tok = idx[row];
  const float* src = embW + (size_t)tok * C;
  float* dst = x + (size_t)row * C;
  for (int c = threadIdx.x; c < C; c += 256) dst[c] = src[c];
}

__global__ void __launch_bounds__(256) ln_kernel(const float* __restrict__ x,
    float* __restrict__ y, const float* __restrict__ s, const float* __restrict__ b){
  __shared__ float red[8];
  int row = blockIdx.x, t = threadIdx.x;
  const float* xr = x + (size_t)row * C;
  float a0 = xr[t], a1 = xr[t+256], a2 = xr[t+512];
  float sum = a0+a1+a2;
  float ss  = a0*a0+a1*a1+a2*a2;
  #pragma unroll
  for (int o=32;o>0;o>>=1){ sum += __shfl_down(sum,o); ss += __shfl_down(ss,o); }
  if ((t&63)==0){ red[t>>6] = sum; red[4+(t>>6)] = ss; }
  __syncthreads();
  if (t==0){
    float S = red[0]+red[1]+red[2]+red[3];
    float Q = red[4]+red[5]+red[6]+red[7];
    float m = S/(float)C;
    float var = Q/(float)C - m*m;
    red[0]=m; red[1]=rsqrtf(var+1e-5f);
  }
  __syncthreads();
  float m = red[0], rs = red[1];
  float* yr = y + (size_t)row*C;
  yr[t]     = (a0-m)*rs*s[t]     + b[t];
  yr[t+256] = (a1-m)*rs*s[t+256] + b[t+256];
  yr[t+512] = (a2-m)*rs*s[t+512] + b[t+512];
}

// RWKV decayed kv scan: one thread per (b,c)
__global__ void __launch_bounds__(256) scan_kernel(const float* __restrict__ k,
    const float* __restrict__ v, const float* __restrict__ dec, float* __restrict__ st){
  int gid = blockIdx.x*256 + threadIdx.x;   // 0..B*C-1
  int b = gid / C, c = gid % C;
  float d = sigf(dec[c]);
  float s = 0.f;
  size_t o = (size_t)b*Tt*C + c;
  #pragma unroll 8
  for (int t=0;t<Tt;t++,o+=C){
    s = d*s + k[o]*v[o];
    st[o] = s;
  }
}

__global__ void __launch_bounds__(256) ew_copy(const float* __restrict__ a, float* __restrict__ b){
  size_t i = (size_t)blockIdx.x*256 + threadIdx.x; b[i] = a[i];
}
__global__ void __launch_bounds__(256) ew_vmix(float* __restrict__ v, const float* __restrict__ vf){
  size_t i = (size_t)blockIdx.x*256 + threadIdx.x; v[i] = 0.5f*(v[i]+vf[i]);
}
__global__ void __launch_bounds__(256) ew_rs(float* __restrict__ r, const float* __restrict__ st){
  size_t i = (size_t)blockIdx.x*256 + threadIdx.x; r[i] = st[i] * sigf(r[i]);
}

__global__ void zero_kernel(int* cnt){ if (threadIdx.x < Ee) cnt[threadIdx.x] = 0; }

__global__ void offsets_kernel(const int* __restrict__ cnt, int* __restrict__ off){
  if (threadIdx.x==0){ int a=0; for (int e=0;e<Ee;e++){ off[e]=a; a+=cnt[e]; } }
}

// routing: conf/affinity/bids/top2 per token; appends to per-expert lists
__global__ void __launch_bounds__(64) route_kernel(const float* __restrict__ h,
    const float* __restrict__ confW, const float* __restrict__ confB,
    const float* __restrict__ Wa, const float* __restrict__ cs,
    int* __restrict__ toks, float* __restrict__ wgt, int* __restrict__ cnt){
  int row = blockIdx.x, lane = threadIdx.x;
  const float* hr = h + (size_t)row*C;
  float hv[12];
  #pragma unroll
  for (int j=0;j<12;j++) hv[j] = hr[j*64+lane];
  float cssum = 0.f;
  #pragma unroll
  for (int e=0;e<Ee;e++) cssum += cs[e];
  float bids[Ee];
  #pragma unroll
  for (int e=0;e<Ee;e++){
    const float* cw = confW + (size_t)e*C;
    float sc=0.f, sa=0.f;
    #pragma unroll
    for (int j=0;j<12;j++){
      int c = j*64+lane;
      sc += hv[j]*cw[c];
      sa += hv[j]*Wa[(size_t)c*Ee + e];
    }
    #pragma unroll
    for (int o=32;o>0;o>>=1){ sc += __shfl_down(sc,o); sa += __shfl_down(sa,o); }
    bids[e] = sigf(sc + confB[e]) * (cs[e]/cssum) + sa;   // valid on lane 0
  }
  if (lane==0){
    int e0=0; float b0=bids[0];
    #pragma unroll
    for (int e=1;e<Ee;e++) if (bids[e] > b0){ b0=bids[e]; e0=e; }
    int e1=-1; float b1=-3.4e38f;
    #pragma unroll
    for (int e=0;e<Ee;e++) if (e!=e0 && bids[e] > b1){ b1=bids[e]; e1=e; }
    float w0 = 1.f/(1.f+expf(b1-b0));   // softmax over [b0,b1], b0 >= b1
    int p0 = atomicAdd(&cnt[e0],1); toks[e0*CAP+p0]=row; wgt[e0*CAP+p0]=w0;
    int p1 = atomicAdd(&cnt[e1],1); toks[e1*CAP+p1]=row; wgt[e1*CAP+p1]=1.f-w0;
  }
}

// ---------------- generic tiled SGEMM ----------------
// C[M,N] = A[M,K] @ B[K,N], all row-major, ld == logical width.
// ASRC: 0=direct row, 1=gather via toks[e*CAP+row], 2=segmented (off[e]+row)
// CDST: 0=direct, 1=segmented, 2=scatter via toks (weighted)
// EPI:  0=store, 1=C+=acc, 2=C=tanh(C+acc), 3=relu(acc)^2, 4=silu(acc),
//       5=acc*aux[segrow], 6=atomicAdd(C, w*acc)
template<int ASRC,int CDST,int EPI>
__global__ void __launch_bounds__(256) gemm_kernel(
    const float* __restrict__ A, const float* __restrict__ Bm, float* __restrict__ Cm,
    int M, int N, int K, long strideB,
    const float* __restrict__ aux,
    const int* __restrict__ toks, const float* __restrict__ wgt,
    const int* __restrict__ cnt, const int* __restrict__ off, int ebase)
{
  const int z = blockIdx.z;
  const int e = ebase + z;
  int Mloc = M;
  if (cnt) Mloc = cnt[e];
  const int rt = blockIdx.x, ct = blockIdx.y;
  if (rt*128 >= Mloc) return;
  const float* Bz = Bm + (size_t)z * (size_t)strideB;

  __shared__ float As[16][132];
  __shared__ float Bs[16][132];

  const int tid = threadIdx.x;
  const int tx = tid & 15, ty = tid >> 4;

  int aoff = 0;
  if (ASRC==2 || CDST==1 || EPI==5) aoff = off[e];

  const int lr0 = tid >> 2;
  const int kk4 = (tid & 3) * 4;
  int arow[2]; bool avalid[2];
  #pragma unroll
  for (int rr=0;rr<2;rr++){
    int gr = rt*128 + lr0 + rr*64;
    avalid[rr] = gr < Mloc;
    int ar = gr;
    if (ASRC==1) ar = avalid[rr] ? toks[e*CAP+gr] : 0;
    else if (ASRC==2) ar = aoff + gr;
    arow[rr] = ar;
  }

  float acc[8][8];
  #pragma unroll
  for (int i=0;i<8;i++)
    #pragma unroll
    for (int j=0;j<8;j++) acc[i][j]=0.f;

  const bool vecB = ((N & 127) == 0);   // all non-head GEMMs

  for (int k0=0; k0<K; k0+=16){
    #pragma unroll
    for (int rr=0;rr<2;rr++){
      float4 av = make_float4(0.f,0.f,0.f,0.f);
      if (avalid[rr]) av = *reinterpret_cast<const float4*>(A + (size_t)arow[rr]*K + (k0 + kk4));
      int lr = lr0 + rr*64;
      As[kk4+0][lr]=av.x; As[kk4+1][lr]=av.y; As[kk4+2][lr]=av.z; As[kk4+3][lr]=av.w;
    }
    #pragma unroll
    for (int rr=0;rr<2;rr++){
      int f4 = tid + rr*256;
      int kb = f4 >> 5, c4 = f4 & 31;
      int n = ct*128 + c4*4;
      const float* bp = Bz + (size_t)(k0+kb)*N;
      float4 bv;
      if (vecB){
        bv = *reinterpret_cast<const float4*>(bp + n);
      } else {
        bv.x = (n+0<N)? bp[n+0] : 0.f;
        bv.y = (n+1<N)? bp[n+1] : 0.f;
        bv.z = (n+2<N)? bp[n+2] : 0.f;
        bv.w = (n+3<N)? bp[n+3] : 0.f;
      }
      *reinterpret_cast<float4*>(&Bs[kb][c4*4]) = bv;
    }
    __syncthreads();
    #pragma unroll
    for (int kk=0;kk<16;kk++){
      float a[8], b[8];
      *reinterpret_cast<float4*>(&a[0]) = *reinterpret_cast<const float4*>(&As[kk][ty*4]);
      *reinterpret_cast<float4*>(&a[4]) = *reinterpret_cast<const float4*>(&As[kk][ty*4+64]);
      *reinterpret_cast<float4*>(&b[0]) = *reinterpret_cast<const float4*>(&Bs[kk][tx*4]);
      *reinterpret_cast<float4*>(&b[4]) = *reinterpret_cast<const float4*>(&Bs[kk][tx*4+64]);
      #pragma unroll
      for (int i=0;i<8;i++)
        #pragma unroll
        for (int j=0;j<8;j++) acc[i][j] = fmaf(a[i], b[j], acc[i][j]);
    }
    __syncthreads();
  }

  #pragma unroll
  for (int i=0;i<8;i++){
    int lr = ty*4 + (i&3) + (i>>2)*64;
    int gr = rt*128 + lr;
    if (gr >= Mloc) continue;
    size_t crow;
    float w = 1.f;
    if (CDST==2){ int tok = toks[e*CAP+gr]; w = wgt[e*CAP+gr]; crow = (size_t)tok; }
    else if (CDST==1) crow = (size_t)(aoff + gr);
    else crow = (size_t)gr;
    float* Crow = Cm + crow * (size_t)N;
    const float* auxrow = nullptr;
    if (EPI==5) auxrow = aux + (size_t)(aoff + gr) * N;
    #pragma unroll
    for (int j=0;j<8;j++){
      int lc = tx*4 + (j&3) + (j>>2)*64;
      int n = ct*128 + lc;
      if (n >= N) continue;
      float va = acc[i][j];
      if (EPI==0) Crow[n] = va;
      else if (EPI==1) Crow[n] += va;
      else if (EPI==2) Crow[n] = tanhf(Crow[n] + va);
      else if (EPI==3){ float rl = fmaxf(va, 0.f); Crow[n] = rl*rl; }
      else if (EPI==4){ Crow[n] = va * sigf(va); }
      else if (EPI==5){ Crow[n] = va * auxrow[n]; }
      else if (EPI==6){ atomicAdd(&Crow[n], w*va); }
    }
  }
}

} // namespace

extern "C" void kernel_launch(void* const* d_in, const int* in_sizes, int n_in,
                              void* d_out, int out_size, void* d_ws, size_t ws_size,
                              hipStream_t stream)
{
  (void)in_sizes; (void)n_in; (void)out_size;
  const int*   idx    = (const int*)  d_in[0];
  const float* cshare = (const float*)d_in[1];
  const float* embW   = (const float*)d_in[2];
  const float* headW  = (const float*)d_in[3];
  const float* ln1s   = (const float*)d_in[4];
  const float* ln1b   = (const float*)d_in[5];
  const float* ln2s   = (const float*)d_in[6];
  const float* ln2b   = (const float*)d_in[7];
  const float* Wr     = (const float*)d_in[8];
  const float* Wk     = (const float*)d_in[9];
  const float* Wv     = (const float*)d_in[10];
  const float* Wo     = (const float*)d_in[11];
  const float* decay  = (const float*)d_in[12];
  const float* ffnW1  = (const float*)d_in[13];
  const float* ffnW2  = (const float*)d_in[14];
  const float* confW  = (const float*)d_in[15];
  const float* confB  = (const float*)d_in[16];
  const float* trA    = (const float*)d_in[17];
  const float* trP    = (const float*)d_in[18];
  const float* trBw   = (const float*)d_in[19];
  // d_in[20] critic_Wd: unused by the reference forward
  const float* Wa     = (const float*)d_in[21];
  const float* bridge = (const float*)d_in[22];
  const float* louts  = (const float*)d_in[23];
  const float* loutb  = (const float*)d_in[24];

  float* dob = (float*)d_out;
  // big activation scratch in d_out (fully consumed before head GEMM writes logits)
  float* hid  = dob;                          // [4096, Hh]
  float* abuf = dob;                          // [4096, H2] (aliases hid, after ffn done)
  float* pz   = dob + (size_t)4096 * H2;      // [4096, H2]

  float* wsf = (float*)d_ws;
  size_t need_bytes = (8*NB + (size_t)2*Ee*CAP + 64) * sizeof(float);
  float *x,*nrm,*r,*k,*v,*vf,*st,*pre; int *toks,*cnt,*off; float *wgt;
  if (ws_size >= need_bytes){
    x=wsf; nrm=x+NB; r=nrm+NB; k=r+NB; v=k+NB; vf=v+NB; st=vf+NB; pre=st+NB;
    toks=(int*)(pre+NB); wgt=(float*)(toks+Ee*CAP); cnt=(int*)(wgt+Ee*CAP); off=cnt+Ee;
  } else {
    // minimal-ws fallback: only nrm + lists in ws, rest in d_out past hid region
    nrm = wsf;
    toks=(int*)(nrm+NB); wgt=(float*)(toks+Ee*CAP); cnt=(int*)(wgt+Ee*CAP); off=cnt+Ee;
    float* p = dob + (size_t)4096*Hh;
    x=p; p+=NB; r=p; p+=NB; k=p; p+=NB; v=p; p+=NB; vf=p; p+=NB; st=p; p+=NB; pre=p;
  }

  const int ewg = (int)(NB/256);

  embed_kernel<<<BT,256,0,stream>>>(idx, embW, x);

  for (int i=0;i<Ll;i++){
    ln_kernel<<<BT,256,0,stream>>>(x, nrm, ln1s+(size_t)i*C, ln1b+(size_t)i*C);
    gemm_kernel<0,0,0><<<dim3(16,6),256,0,stream>>>(nrm, Wr+(size_t)i*C*C, r, BT,C,C, 0, nullptr,nullptr,nullptr,nullptr,nullptr,0);
    gemm_kernel<0,0,0><<<dim3(16,6),256,0,stream>>>(nrm, Wk+(size_t)i*C*C, k, BT,C,C, 0, nullptr,nullptr,nullptr,nullptr,nullptr,0);
    gemm_kernel<0,0,0><<<dim3(16,6),256,0,stream>>>(nrm, Wv+(size_t)i*C*C, v, BT,C,C, 0, nullptr,nullptr,nullptr,nullptr,nullptr,0);
    if (i==0) ew_copy<<<ewg,256,0,stream>>>(v, vf);
    else      ew_vmix<<<ewg,256,0,stream>>>(v, vf);
    scan_kernel<<<(Bb*C)/256,256,0,stream>>>(k, v, decay+(size_t)i*C, st);
    ew_rs<<<ewg,256,0,stream>>>(r, st);
    gemm_kernel<0,0,1><<<dim3(16,6),256,0,stream>>>(r, Wo+(size_t)i*C*C, x, BT,C,C, 0, nullptr,nullptr,nullptr,nullptr,nullptr,0);
    ln_kernel<<<BT,256,0,stream>>>(x, nrm, ln2s+(size_t)i*C, ln2b+(size_t)i*C);

    zero_kernel<<<1,64,0,stream>>>(cnt);
    route_kernel<<<BT,64,0,stream>>>(nrm, confW+(size_t)i*Ee*C, confB+(size_t)i*Ee,
                                     Wa+(size_t)i*C*Ee, cshare+(size_t)i*Ee, toks, wgt, cnt);
    offsets_kernel<<<1,1,0,stream>>>(cnt, off);

    // prefix = tanh(h @ Wb_top + states @ Wb_bot)
    gemm_kernel<0,0,0><<<dim3(16,6),256,0,stream>>>(nrm, bridge, pre, BT,C,C, 0, nullptr,nullptr,nullptr,nullptr,nullptr,0);
    gemm_kernel<0,0,2><<<dim3(16,6),256,0,stream>>>(st, bridge+(size_t)C*C, pre, BT,C,C, 0, nullptr,nullptr,nullptr,nullptr,nullptr,0);

    // ffn experts: hid = relu(h@W1)^2 ; x += w * hid@W2   (top-2 rows only)
    gemm_kernel<1,1,3><<<dim3(16,24,ER),256,0,stream>>>(nrm, ffnW1+(size_t)i*ER*C*Hh, hid,
        CAP,Hh,C, (long)C*Hh, nullptr, toks,wgt,cnt,off, 0);
    gemm_kernel<2,2,6><<<dim3(16,6,ER),256,0,stream>>>(hid, ffnW2+(size_t)i*ER*Hh*C, x,
        CAP,C,Hh, (long)Hh*C, nullptr, toks,wgt,cnt,off, 0);

    // trans experts: a = silu(h@A); pz = (prefix@P)*a; x += w * pz@B
    gemm_kernel<1,1,4><<<dim3(16,12,ET),256,0,stream>>>(nrm, trA+(size_t)i*ET*C*H2, abuf,
        CAP,H2,C, (long)C*H2, nullptr, toks,wgt,cnt,off, ER);
    gemm_kernel<1,1,5><<<dim3(16,12,ET),256,0,stream>>>(pre, trP+(size_t)i*ET*C*H2, pz,
        CAP,H2,C, (long)C*H2, abuf, toks,wgt,cnt,off, ER);
    gemm_kernel<2,2,6><<<dim3(16,6,ET),256,0,stream>>>(pz, trBw+(size_t)i*ET*H2*C, x,
        CAP,C,H2, (long)H2*C, nullptr, toks,wgt,cnt,off, ER);
  }

  ln_kernel<<<BT,256,0,stream>>>(x, nrm, louts, loutb);
  // logits = xout @ head_W  (overwrites all of d_out, including the scratch region)
  gemm_kernel<0,0,0><<<dim3(16,393),256,0,stream>>>(nrm, headW, dob, BT,Vv,C, 0,
      nullptr,nullptr,nullptr,nullptr,nullptr,0);
}